// Round 1
// baseline (812.773 us; speedup 1.0000x reference)
//
#include <hip/hip_runtime.h>
#include <hip/hip_bf16.h>
#include <math.h>

// ---------------------------------------------------------------------------
// SentiGAT fp32 baseline.
// Stages:
//  A1: H = gather(word,object) @ ow_W          (14336x512 @ 512x1024)
//  A2: ow GAT edge-softmax + aggregate -> hout (B,28,512)
//  A3: attn = softmax(uo@uw^T); aligned = colmean(attn)@uw  (B,512)
//  B : ind_norm 5 feats -> x5 (B,5,513)
//  C1: hg = x5 @ g1_W   (2560x513 @ 513x512)
//  C2: 5-node GAT (g1) + relu -> h1
//  C3: hg2 = h1 @ g2_W
//  C4: 5-node GAT (g2)        -> fused (B,2560)
//  D1: hid = relu(fused @ m1_W + m1_b)         (512x2560 @ 2560x512)
//  D2: out = hid @ m2_W + m2_b                 (B,3)
// ---------------------------------------------------------------------------

#define B_SAMP 512

__device__ __forceinline__ float lrelu02(float x) { return x > 0.f ? x : 0.2f * x; }

// ---------------- generic tiled fp32 GEMM: C = A @ B (+bias)(+relu) ---------
// tile 64(M) x 128(N), BK=16, 256 threads, each thread 8x4 outputs.
// mode==1: A rows gathered from word/object concat layout (row length 512).
template <int RELU>
__global__ __launch_bounds__(256) void gemm_f32(
    const float* __restrict__ A, int lda,
    const float* __restrict__ Bm, int ldb,
    float* __restrict__ C, int ldc,
    int M, int N, int K,
    const float* __restrict__ bias,
    int mode, const float* __restrict__ wf, const float* __restrict__ of)
{
    __shared__ float As[64][17];
    __shared__ float Bs[16][128];

    const int tid = threadIdx.x;
    const int n0 = blockIdx.x * 128;
    const int m0 = blockIdx.y * 64;

    const int cg = tid & 31;   // col group (4 cols)
    const int rg = tid >> 5;   // row group (8 rows)

    // A staging map: each thread loads 4 consecutive k of one row
    const int am = tid >> 2;          // 0..63
    const int ak = (tid & 3) * 4;     // 0,4,8,12
    const float* arow;
    {
        int r = m0 + am;
        if (mode == 0) {
            arow = A + (size_t)r * lda;
        } else {
            int b = r / 28, n = r - b * 28;
            arow = (n < 12) ? (wf + ((size_t)b * 12 + n) * 512)
                            : (of + ((size_t)b * 16 + (n - 12)) * 512);
        }
    }
    // B staging map: each thread loads float4 at (bk, bn) and (bk+8, bn)
    const int bn = (tid & 31) * 4;
    const int bk = tid >> 5;          // 0..7

    float acc[8][4];
#pragma unroll
    for (int i = 0; i < 8; ++i)
#pragma unroll
        for (int j = 0; j < 4; ++j) acc[i][j] = 0.f;

    for (int k0 = 0; k0 < K; k0 += 16) {
#pragma unroll
        for (int q = 0; q < 4; ++q) {
            int k = k0 + ak + q;
            As[am][ak + q] = (k < K) ? arow[k] : 0.f;
        }
#pragma unroll
        for (int h = 0; h < 2; ++h) {
            int kk = bk + 8 * h;
            int k = k0 + kk;
            float4 v = make_float4(0.f, 0.f, 0.f, 0.f);
            if (k < K) v = *(const float4*)(Bm + (size_t)k * ldb + n0 + bn);
            *(float4*)&Bs[kk][bn] = v;
        }
        __syncthreads();
#pragma unroll
        for (int kk = 0; kk < 16; ++kk) {
            float4 b4 = *(const float4*)&Bs[kk][cg * 4];
#pragma unroll
            for (int i = 0; i < 8; ++i) {
                float av = As[rg * 8 + i][kk];
                acc[i][0] += av * b4.x;
                acc[i][1] += av * b4.y;
                acc[i][2] += av * b4.z;
                acc[i][3] += av * b4.w;
            }
        }
        __syncthreads();
    }

    float4 bv = make_float4(0.f, 0.f, 0.f, 0.f);
    if (bias) bv = *(const float4*)(bias + n0 + cg * 4);

#pragma unroll
    for (int i = 0; i < 8; ++i) {
        int row = m0 + rg * 8 + i;
        float4 o;
        o.x = acc[i][0] + bv.x;
        o.y = acc[i][1] + bv.y;
        o.z = acc[i][2] + bv.z;
        o.w = acc[i][3] + bv.w;
        if (RELU) {
            o.x = fmaxf(o.x, 0.f); o.y = fmaxf(o.y, 0.f);
            o.z = fmaxf(o.z, 0.f); o.w = fmaxf(o.w, 0.f);
        }
        *(float4*)(C + (size_t)row * ldc + n0 + cg * 4) = o;
    }
}

// ---------------- A2: ow GAT edge softmax + aggregation ---------------------
__global__ __launch_bounds__(256) void ow_gat(
    const float* __restrict__ H,     // [B*28, 1024]  (head-major halves)
    const float* __restrict__ asrc,  // [2,512]
    const float* __restrict__ adst,  // [2,512]
    const float* __restrict__ bias,  // [512]
    float* __restrict__ hout)        // [B*28, 512]
{
    const int b = blockIdx.x;
    __shared__ float ssrc[28][2];
    __shared__ float sdst[28][2];
    __shared__ float alpha[16][2][13];  // [word][head][12 obj + self]

    const int tid = threadIdx.x;
    const int lane = tid & 63;
    const int wave = tid >> 6;
    const float* Hb = H + (size_t)b * 28 * 1024;

    // 112 dot products of length 512
    for (int p = wave; p < 112; p += 4) {
        int n = p >> 2, h = (p >> 1) & 1, ty = p & 1;
        const float* hv = Hb + n * 1024 + h * 512;
        const float* av = (ty ? adst : asrc) + h * 512;
        float s = 0.f;
#pragma unroll
        for (int j = 0; j < 8; ++j) s += hv[lane + 64 * j] * av[lane + 64 * j];
        for (int off = 32; off > 0; off >>= 1) s += __shfl_down(s, off, 64);
        if (lane == 0) { if (ty) sdst[n][h] = s; else ssrc[n][h] = s; }
    }
    __syncthreads();

    if (tid < 32) {
        int w = tid >> 1, h = tid & 1, node = 12 + w;
        float e[13];
        float sd = sdst[node][h];
        float mx = -1e30f;
        for (int j = 0; j < 12; ++j) {
            float x = ssrc[j][h] + sd;
            e[j] = lrelu02(x);
            mx = fmaxf(mx, e[j]);
        }
        {
            float x = ssrc[node][h] + sd;
            e[12] = lrelu02(x);
            mx = fmaxf(mx, e[12]);
        }
        float den = 0.f;
        for (int j = 0; j < 13; ++j) { e[j] = expf(e[j] - mx); den += e[j]; }
        float inv = 1.f / den;
        for (int j = 0; j < 13; ++j) alpha[w][h][j] = e[j] * inv;
    }
    __syncthreads();

    for (int d = tid; d < 512; d += 256) {
        float bd = bias[d];
        // obj nodes: only self loop -> alpha = 1
        for (int n = 0; n < 12; ++n) {
            float v = 0.5f * (Hb[n * 1024 + d] + Hb[n * 1024 + 512 + d]) + bd;
            hout[((size_t)b * 28 + n) * 512 + d] = v;
        }
        for (int w = 0; w < 16; ++w) {
            int node = 12 + w;
            float a0 = 0.f, a1 = 0.f;
            for (int j = 0; j < 12; ++j) {
                a0 += alpha[w][0][j] * Hb[j * 1024 + d];
                a1 += alpha[w][1][j] * Hb[j * 1024 + 512 + d];
            }
            a0 += alpha[w][0][12] * Hb[node * 1024 + d];
            a1 += alpha[w][1][12] * Hb[node * 1024 + 512 + d];
            hout[((size_t)b * 28 + node) * 512 + d] = 0.5f * (a0 + a1) + bd;
        }
    }
}

// ---------------- A3: 12x16 attention + aligned -----------------------------
__global__ __launch_bounds__(256) void attn_align(
    const float* __restrict__ hout, float* __restrict__ aligned)
{
    const int b = blockIdx.x;
    __shared__ float uo[12][513];
    __shared__ float uw[16][513];
    __shared__ float S[12][16];
    __shared__ float w16[16];

    const int tid = threadIdx.x;
    const float* hb = hout + (size_t)b * 28 * 512;

    for (int idx = tid; idx < 28 * 512; idx += 256) {
        int n = idx >> 9, d = idx & 511;
        float v = hb[idx];
        if (n < 12) uo[n][d] = v; else uw[n - 12][d] = v;
    }
    __syncthreads();

    if (tid < 192) {
        int i = tid >> 4, j = tid & 15;
        float s = 0.f;
        for (int d = 0; d < 512; ++d) s += uo[i][d] * uw[j][d];
        S[i][j] = s;
    }
    __syncthreads();

    if (tid < 12) {
        float mx = -1e30f;
        for (int j = 0; j < 16; ++j) mx = fmaxf(mx, S[tid][j]);
        float den = 0.f;
        for (int j = 0; j < 16; ++j) { float p = expf(S[tid][j] - mx); S[tid][j] = p; den += p; }
        float inv = 1.f / den;
        for (int j = 0; j < 16; ++j) S[tid][j] *= inv;
    }
    __syncthreads();

    if (tid < 16) {
        float s = 0.f;
        for (int i = 0; i < 12; ++i) s += S[i][tid];
        w16[tid] = s * (1.f / 12.f);
    }
    __syncthreads();

    for (int d = tid; d < 512; d += 256) {
        float s = 0.f;
#pragma unroll
        for (int j = 0; j < 16; ++j) s += w16[j] * uw[j][d];
        aligned[(size_t)b * 512 + d] = s;
    }
}

// ---------------- B: ind_norm -> x5 (B,5,513) -------------------------------
__global__ __launch_bounds__(256) void build_x5(
    const float* __restrict__ t, const float* __restrict__ im,
    const float* __restrict__ it, const float* __restrict__ fa,
    const float* __restrict__ al, float* __restrict__ x5)
{
    int gw = (int)((blockIdx.x * 256 + threadIdx.x) >> 6);
    int lane = threadIdx.x & 63;
    if (gw >= B_SAMP * 5) return;
    int b = gw / 5, f = gw - b * 5;
    const float* src = (f == 0) ? t : (f == 1) ? im : (f == 2) ? it : (f == 3) ? fa : al;
    src += (size_t)b * 512;

    float vals[8];
    float sum = 0.f, sq = 0.f;
#pragma unroll
    for (int j = 0; j < 8; ++j) {
        float v = src[lane + 64 * j];
        vals[j] = v;
        sum += v;
        sq += v * v;
    }
#pragma unroll
    for (int off = 32; off > 0; off >>= 1) {
        sum += __shfl_xor(sum, off, 64);
        sq  += __shfl_xor(sq,  off, 64);
    }
    float v = (sum != 0.f) ? 1.f : 0.f;
    float nrm = sqrtf(sq + v * v);
    nrm = fmaxf(nrm, 1e-12f);
    float inv = 1.f / nrm;
    float* dst = x5 + ((size_t)b * 5 + f) * 513;
#pragma unroll
    for (int j = 0; j < 8; ++j) dst[lane + 64 * j] = vals[j] * inv;
    if (lane == 0) dst[512] = v * inv;
}

// ---------------- C2/C4: 5-node complete-graph GAT --------------------------
template <int RELU>
__global__ __launch_bounds__(256) void g5_gat(
    const float* __restrict__ Hg,   // [B*5,512]
    const float* __restrict__ asrc, // [512]
    const float* __restrict__ adst, // [512]
    const float* __restrict__ bias, // [512]
    float* __restrict__ out)        // [B*5,512]
{
    const int b = blockIdx.x;
    __shared__ float ss[5], sd[5];
    __shared__ float alpha[5][5];   // [dst][src]

    const int tid = threadIdx.x;
    const int lane = tid & 63;
    const int wave = tid >> 6;
    const float* Hb = Hg + (size_t)b * 5 * 512;

    for (int p = wave; p < 10; p += 4) {
        int n = p >> 1, ty = p & 1;
        const float* hv = Hb + n * 512;
        const float* av = ty ? adst : asrc;
        float s = 0.f;
#pragma unroll
        for (int j = 0; j < 8; ++j) s += hv[lane + 64 * j] * av[lane + 64 * j];
        for (int off = 32; off > 0; off >>= 1) s += __shfl_down(s, off, 64);
        if (lane == 0) { if (ty) sd[n] = s; else ss[n] = s; }
    }
    __syncthreads();

    if (tid < 5) {
        int dn = tid;
        float e[5];
        float mx = -1e30f;
        for (int s = 0; s < 5; ++s) {
            float x = ss[s] + sd[dn];
            e[s] = lrelu02(x);
            mx = fmaxf(mx, e[s]);
        }
        float den = 0.f;
        for (int s = 0; s < 5; ++s) { e[s] = expf(e[s] - mx); den += e[s]; }
        float inv = 1.f / den;
        for (int s = 0; s < 5; ++s) alpha[dn][s] = e[s] * inv;
    }
    __syncthreads();

    for (int d = tid; d < 512; d += 256) {
        float h0 = Hb[0 * 512 + d], h1 = Hb[1 * 512 + d], h2 = Hb[2 * 512 + d];
        float h3 = Hb[3 * 512 + d], h4 = Hb[4 * 512 + d];
        float bd = bias[d];
#pragma unroll
        for (int dn = 0; dn < 5; ++dn) {
            float v = alpha[dn][0] * h0 + alpha[dn][1] * h1 + alpha[dn][2] * h2 +
                      alpha[dn][3] * h3 + alpha[dn][4] * h4 + bd;
            if (RELU) v = fmaxf(v, 0.f);
            out[((size_t)b * 5 + dn) * 512 + d] = v;
        }
    }
}

// ---------------- D2: out = hid @ m2_W + m2_b -------------------------------
__global__ __launch_bounds__(64) void final_k(
    const float* __restrict__ hid, const float* __restrict__ w,
    const float* __restrict__ bvec, float* __restrict__ out)
{
    const int b = blockIdx.x;
    const int lane = threadIdx.x;
    const float* h = hid + (size_t)b * 512;
    float a0 = 0.f, a1 = 0.f, a2 = 0.f;
#pragma unroll
    for (int j = 0; j < 8; ++j) {
        int d = lane + 64 * j;
        float x = h[d];
        a0 += x * w[d * 3 + 0];
        a1 += x * w[d * 3 + 1];
        a2 += x * w[d * 3 + 2];
    }
    for (int off = 32; off > 0; off >>= 1) {
        a0 += __shfl_down(a0, off, 64);
        a1 += __shfl_down(a1, off, 64);
        a2 += __shfl_down(a2, off, 64);
    }
    if (lane == 0) {
        out[b * 3 + 0] = a0 + bvec[0];
        out[b * 3 + 1] = a1 + bvec[1];
        out[b * 3 + 2] = a2 + bvec[2];
    }
}

extern "C" void kernel_launch(void* const* d_in, const int* in_sizes, int n_in,
                              void* d_out, int out_size, void* d_ws, size_t ws_size,
                              hipStream_t stream) {
    const float* text   = (const float*)d_in[0];
    const float* image  = (const float*)d_in[1];
    const float* imgtxt = (const float*)d_in[2];
    const float* face   = (const float*)d_in[3];
    const float* word   = (const float*)d_in[4];
    const float* obj    = (const float*)d_in[5];
    const float* ow_W    = (const float*)d_in[6];
    const float* ow_asrc = (const float*)d_in[7];
    const float* ow_adst = (const float*)d_in[8];
    const float* ow_b    = (const float*)d_in[9];
    const float* g1_W    = (const float*)d_in[10];
    const float* g1_asrc = (const float*)d_in[11];
    const float* g1_adst = (const float*)d_in[12];
    const float* g1_b    = (const float*)d_in[13];
    const float* g2_W    = (const float*)d_in[14];
    const float* g2_asrc = (const float*)d_in[15];
    const float* g2_adst = (const float*)d_in[16];
    const float* g2_b    = (const float*)d_in[17];
    const float* m1_W    = (const float*)d_in[18];
    const float* m1_b    = (const float*)d_in[19];
    const float* m2_W    = (const float*)d_in[20];
    const float* m2_b    = (const float*)d_in[21];

    float* ws = (float*)d_ws;
    float* H      = ws;                  // 512*28*1024 = 14,680,064
    float* hout   = H + 14680064;        // 512*28*512  =  7,340,032
    float* algn   = hout + 7340032;      // 512*512     =    262,144
    float* x5     = algn + 262144;       // 512*5*513   =  1,313,280
    float* hg     = x5 + 1313280;        // 512*5*512   =  1,310,720
    float* h1     = hg + 1310720;        // 1,310,720
    float* fused  = h1 + 1310720;        // 1,310,720
    float* hid    = fused + 1310720;     // 262,144

    // A1: H = X @ ow_W   (gathered A)
    gemm_f32<0><<<dim3(1024 / 128, 14336 / 64), 256, 0, stream>>>(
        nullptr, 0, ow_W, 1024, H, 1024, 14336, 1024, 512, nullptr, 1, word, obj);
    // A2
    ow_gat<<<B_SAMP, 256, 0, stream>>>(H, ow_asrc, ow_adst, ow_b, hout);
    // A3
    attn_align<<<B_SAMP, 256, 0, stream>>>(hout, algn);
    // B
    build_x5<<<(B_SAMP * 5) / 4, 256, 0, stream>>>(text, image, imgtxt, face, algn, x5);
    // C1
    gemm_f32<0><<<dim3(512 / 128, 2560 / 64), 256, 0, stream>>>(
        x5, 513, g1_W, 512, hg, 512, 2560, 512, 513, nullptr, 0, nullptr, nullptr);
    // C2
    g5_gat<1><<<B_SAMP, 256, 0, stream>>>(hg, g1_asrc, g1_adst, g1_b, h1);
    // C3
    gemm_f32<0><<<dim3(512 / 128, 2560 / 64), 256, 0, stream>>>(
        h1, 512, g2_W, 512, hg, 512, 2560, 512, 512, nullptr, 0, nullptr, nullptr);
    // C4
    g5_gat<0><<<B_SAMP, 256, 0, stream>>>(hg, g2_asrc, g2_adst, g2_b, fused);
    // D1: hid = relu(fused @ m1_W + m1_b)
    gemm_f32<1><<<dim3(512 / 128, 512 / 64), 256, 0, stream>>>(
        fused, 2560, m1_W, 512, hid, 512, 512, 512, 2560, m1_b, 0, nullptr, nullptr);
    // D2
    final_k<<<B_SAMP, 64, 0, stream>>>(hid, m2_W, m2_b, (float*)d_out);
}

// Round 2
// 250.194 us; speedup vs baseline: 3.2486x; 3.2486x over previous
//
#include <hip/hip_runtime.h>
#include <hip/hip_bf16.h>
#include <math.h>

// ---------------------------------------------------------------------------
// SentiGAT — round 1: all GEMMs via bf16 MFMA (fp32 accumulate).
//  W*: weights pre-transposed+converted to bf16 [N][Kpad] (wt_conv)
//  A1: H = gather(word,object) @ ow_W          (14336x1024x512)  MFMA
//  A2: ow GAT edge-softmax + aggregate -> hout (B,28,512)        fp32
//  A3: attn = softmax(uo@uw^T); aligned        (B,512)           fp32
//  B : ind_norm 5 feats -> x5 (B*5,544) fp32, zero-padded K tail
//  C1: hg = x5 @ g1_W   (2560x512x544)  MFMA
//  C2: 5-node GAT (g1) + relu -> h1                              fp32
//  C3: hg = h1 @ g2_W   (2560x512x512)  MFMA
//  C4: 5-node GAT (g2)        -> fused                           fp32
//  D1: hid = relu(fused @ m1_W + m1_b) (512x512x2560)  MFMA 64x64 tile
//  D2: out = hid @ m2_W + m2_b                 (B,3)             fp32
// ---------------------------------------------------------------------------

#define B_SAMP 512

typedef short short8 __attribute__((ext_vector_type(8)));
typedef float floatx4 __attribute__((ext_vector_type(4)));

__device__ __forceinline__ float lrelu02(float x) { return x > 0.f ? x : 0.2f * x; }

__device__ __forceinline__ unsigned short cvt_bf16(float f) {
    union { float f; unsigned int u; } v; v.f = f;
    unsigned int u = v.u;
    return (unsigned short)((u + 0x7FFFu + ((u >> 16) & 1u)) >> 16);  // RNE
}

// ---------------- weight transpose+convert: fp32 [K][N] -> bf16 [N][Kpad] ---
__global__ __launch_bounds__(256) void wt_conv(
    const float* __restrict__ W, int K, int N, int Kpad,
    unsigned short* __restrict__ Wt)
{
    __shared__ float T[32][33];
    const int tid = threadIdx.x;
    const int k0 = blockIdx.x * 32;
    const int n0 = blockIdx.y * 32;
    {
        int kr = tid >> 3, nc = (tid & 7) * 4;
        float4 v = make_float4(0.f, 0.f, 0.f, 0.f);
        if (k0 + kr < K) v = *(const float4*)(W + (size_t)(k0 + kr) * N + n0 + nc);
        T[nc + 0][kr] = v.x; T[nc + 1][kr] = v.y;
        T[nc + 2][kr] = v.z; T[nc + 3][kr] = v.w;
    }
    __syncthreads();
    {
        int nr = tid >> 3, kc = (tid & 7) * 4;
        ushort4 w;
        w.x = cvt_bf16(T[nr][kc + 0]);
        w.y = cvt_bf16(T[nr][kc + 1]);
        w.z = cvt_bf16(T[nr][kc + 2]);
        w.w = cvt_bf16(T[nr][kc + 3]);
        *(ushort4*)(Wt + (size_t)(n0 + nr) * Kpad + k0 + kc) = w;
    }
}

// ---------------- bf16 MFMA GEMM: C = A @ Bt^T (+bias)(+relu) ---------------
// A fp32 [M][lda] (or gathered rows of len 512), Bt bf16 [N][ldbt], C fp32.
// BK=32. 256 threads = 4 waves in 2x2, each wave (BM/2)x(BN/2).
template <int BM, int BN, int RELU, int GATHER>
__global__ __launch_bounds__(256) void gemm_bf16(
    const float* __restrict__ A, int lda,
    const unsigned short* __restrict__ Bt, int ldbt,
    float* __restrict__ C, int ldc,
    int M, int N, int K,
    const float* __restrict__ bias,
    const float* __restrict__ wf, const float* __restrict__ of)
{
    constexpr int WM = BM / 2, WN = BN / 2;
    constexpr int MF = WM / 16, NF = WN / 16;
    constexpr int AI = BM / 32, BI = BN / 32;

    __shared__ unsigned short As[BM][32];
    __shared__ unsigned short Bs[BN][32];

    const int tid = threadIdx.x;
    const int n0 = blockIdx.x * BN;
    const int m0 = blockIdx.y * BM;
    const int lane = tid & 63;
    const int wid = tid >> 6;
    const int wm = (wid & 1) * WM;
    const int wn = (wid >> 1) * WN;

    const int sr = tid >> 3;        // staging row 0..31
    const int sc = (tid & 7) * 4;   // staging col (x4 elts)

    const float* arow[AI];
#pragma unroll
    for (int i = 0; i < AI; ++i) {
        int r = m0 + sr + i * 32;
        if (GATHER) {
            int b = r / 28, n = r - b * 28;
            arow[i] = (n < 12) ? (wf + ((size_t)b * 12 + n) * 512)
                               : (of + ((size_t)b * 16 + (n - 12)) * 512);
        } else {
            arow[i] = A + (size_t)r * lda;
        }
    }

    floatx4 acc[MF][NF];
#pragma unroll
    for (int i = 0; i < MF; ++i)
#pragma unroll
        for (int j = 0; j < NF; ++j) acc[i][j] = (floatx4){0.f, 0.f, 0.f, 0.f};

    const int fr = lane & 15;
    const int kq = (lane >> 4) * 8;

    for (int k0 = 0; k0 < K; k0 += 32) {
#pragma unroll
        for (int i = 0; i < AI; ++i) {
            float4 v = *(const float4*)(arow[i] + k0 + sc);
            ushort4 w;
            w.x = cvt_bf16(v.x); w.y = cvt_bf16(v.y);
            w.z = cvt_bf16(v.z); w.w = cvt_bf16(v.w);
            *(ushort4*)&As[sr + i * 32][sc] = w;
        }
#pragma unroll
        for (int i = 0; i < BI; ++i) {
            ushort4 w = *(const ushort4*)(Bt + (size_t)(n0 + sr + i * 32) * ldbt + k0 + sc);
            *(ushort4*)&Bs[sr + i * 32][sc] = w;
        }
        __syncthreads();

        short8 af[MF], bfr[NF];
#pragma unroll
        for (int i = 0; i < MF; ++i)
            af[i] = *(const short8*)&As[wm + i * 16 + fr][kq];
#pragma unroll
        for (int j = 0; j < NF; ++j)
            bfr[j] = *(const short8*)&Bs[wn + j * 16 + fr][kq];
#pragma unroll
        for (int i = 0; i < MF; ++i)
#pragma unroll
            for (int j = 0; j < NF; ++j)
                acc[i][j] = __builtin_amdgcn_mfma_f32_16x16x32_bf16(
                    af[i], bfr[j], acc[i][j], 0, 0, 0);
        __syncthreads();
    }

    const int fq = lane >> 4;
#pragma unroll
    for (int i = 0; i < MF; ++i) {
#pragma unroll
        for (int j = 0; j < NF; ++j) {
#pragma unroll
            for (int q = 0; q < 4; ++q) {
                int row = m0 + wm + i * 16 + fq * 4 + q;
                int col = n0 + wn + j * 16 + fr;
                float v = acc[i][j][q];
                if (bias) v += bias[col];
                if (RELU) v = fmaxf(v, 0.f);
                C[(size_t)row * ldc + col] = v;
            }
        }
    }
}

// ---------------- A2: ow GAT edge softmax + aggregation ---------------------
__global__ __launch_bounds__(256) void ow_gat(
    const float* __restrict__ H,     // [B*28, 1024]
    const float* __restrict__ asrc,  // [2,512]
    const float* __restrict__ adst,  // [2,512]
    const float* __restrict__ bias,  // [512]
    float* __restrict__ hout)        // [B*28, 512]
{
    const int b = blockIdx.x;
    __shared__ float ssrc[28][2];
    __shared__ float sdst[28][2];
    __shared__ float alpha[16][2][13];

    const int tid = threadIdx.x;
    const int lane = tid & 63;
    const int wave = tid >> 6;
    const float* Hb = H + (size_t)b * 28 * 1024;

    for (int p = wave; p < 112; p += 4) {
        int n = p >> 2, h = (p >> 1) & 1, ty = p & 1;
        const float* hv = Hb + n * 1024 + h * 512;
        const float* av = (ty ? adst : asrc) + h * 512;
        float s = 0.f;
#pragma unroll
        for (int j = 0; j < 8; ++j) s += hv[lane + 64 * j] * av[lane + 64 * j];
        for (int off = 32; off > 0; off >>= 1) s += __shfl_down(s, off, 64);
        if (lane == 0) { if (ty) sdst[n][h] = s; else ssrc[n][h] = s; }
    }
    __syncthreads();

    if (tid < 32) {
        int w = tid >> 1, h = tid & 1, node = 12 + w;
        float e[13];
        float sd = sdst[node][h];
        float mx = -1e30f;
        for (int j = 0; j < 12; ++j) {
            e[j] = lrelu02(ssrc[j][h] + sd);
            mx = fmaxf(mx, e[j]);
        }
        e[12] = lrelu02(ssrc[node][h] + sd);
        mx = fmaxf(mx, e[12]);
        float den = 0.f;
        for (int j = 0; j < 13; ++j) { e[j] = expf(e[j] - mx); den += e[j]; }
        float inv = 1.f / den;
        for (int j = 0; j < 13; ++j) alpha[w][h][j] = e[j] * inv;
    }
    __syncthreads();

    for (int d = tid; d < 512; d += 256) {
        float bd = bias[d];
        for (int n = 0; n < 12; ++n) {
            float v = 0.5f * (Hb[n * 1024 + d] + Hb[n * 1024 + 512 + d]) + bd;
            hout[((size_t)b * 28 + n) * 512 + d] = v;
        }
        for (int w = 0; w < 16; ++w) {
            int node = 12 + w;
            float a0 = 0.f, a1 = 0.f;
            for (int j = 0; j < 12; ++j) {
                a0 += alpha[w][0][j] * Hb[j * 1024 + d];
                a1 += alpha[w][1][j] * Hb[j * 1024 + 512 + d];
            }
            a0 += alpha[w][0][12] * Hb[node * 1024 + d];
            a1 += alpha[w][1][12] * Hb[node * 1024 + 512 + d];
            hout[((size_t)b * 28 + node) * 512 + d] = 0.5f * (a0 + a1) + bd;
        }
    }
}

// ---------------- A3: 12x16 attention + aligned -----------------------------
__global__ __launch_bounds__(256) void attn_align(
    const float* __restrict__ hout, float* __restrict__ aligned)
{
    const int b = blockIdx.x;
    __shared__ float uo[12][513];
    __shared__ float uw[16][513];
    __shared__ float S[12][16];
    __shared__ float w16[16];

    const int tid = threadIdx.x;
    const float* hb = hout + (size_t)b * 28 * 512;

    for (int idx = tid; idx < 28 * 512; idx += 256) {
        int n = idx >> 9, d = idx & 511;
        float v = hb[idx];
        if (n < 12) uo[n][d] = v; else uw[n - 12][d] = v;
    }
    __syncthreads();

    if (tid < 192) {
        int i = tid >> 4, j = tid & 15;
        float s = 0.f;
        for (int d = 0; d < 512; ++d) s += uo[i][d] * uw[j][d];
        S[i][j] = s;
    }
    __syncthreads();

    if (tid < 12) {
        float mx = -1e30f;
        for (int j = 0; j < 16; ++j) mx = fmaxf(mx, S[tid][j]);
        float den = 0.f;
        for (int j = 0; j < 16; ++j) { float p = expf(S[tid][j] - mx); S[tid][j] = p; den += p; }
        float inv = 1.f / den;
        for (int j = 0; j < 16; ++j) S[tid][j] *= inv;
    }
    __syncthreads();

    if (tid < 16) {
        float s = 0.f;
        for (int i = 0; i < 12; ++i) s += S[i][tid];
        w16[tid] = s * (1.f / 12.f);
    }
    __syncthreads();

    for (int d = tid; d < 512; d += 256) {
        float s = 0.f;
#pragma unroll
        for (int j = 0; j < 16; ++j) s += w16[j] * uw[j][d];
        aligned[(size_t)b * 512 + d] = s;
    }
}

// ---------------- B: ind_norm -> x5 (B*5, 544) fp32, zero K-tail ------------
__global__ __launch_bounds__(256) void build_x5(
    const float* __restrict__ t, const float* __restrict__ im,
    const float* __restrict__ it, const float* __restrict__ fa,
    const float* __restrict__ al, float* __restrict__ x5)
{
    int gw = (int)((blockIdx.x * 256 + threadIdx.x) >> 6);
    int lane = threadIdx.x & 63;
    if (gw >= B_SAMP * 5) return;
    int b = gw / 5, f = gw - b * 5;
    const float* src = (f == 0) ? t : (f == 1) ? im : (f == 2) ? it : (f == 3) ? fa : al;
    src += (size_t)b * 512;

    float vals[8];
    float sum = 0.f, sq = 0.f;
#pragma unroll
    for (int j = 0; j < 8; ++j) {
        float v = src[lane + 64 * j];
        vals[j] = v;
        sum += v;
        sq += v * v;
    }
#pragma unroll
    for (int off = 32; off > 0; off >>= 1) {
        sum += __shfl_xor(sum, off, 64);
        sq  += __shfl_xor(sq,  off, 64);
    }
    float v = (sum != 0.f) ? 1.f : 0.f;
    float nrm = fmaxf(sqrtf(sq + v * v), 1e-12f);
    float inv = 1.f / nrm;
    float* dst = x5 + (size_t)gw * 544;
#pragma unroll
    for (int j = 0; j < 8; ++j) dst[lane + 64 * j] = vals[j] * inv;
    if (lane == 0) dst[512] = v * inv;
    else if (lane < 32) dst[512 + lane] = 0.f;   // zero K-pad tail (513..543)
}

// ---------------- C2/C4: 5-node complete-graph GAT --------------------------
template <int RELU>
__global__ __launch_bounds__(256) void g5_gat(
    const float* __restrict__ Hg,   // [B*5,512]
    const float* __restrict__ asrc, const float* __restrict__ adst,
    const float* __restrict__ bias, float* __restrict__ out)
{
    const int b = blockIdx.x;
    __shared__ float ss[5], sd[5];
    __shared__ float alpha[5][5];

    const int tid = threadIdx.x;
    const int lane = tid & 63;
    const int wave = tid >> 6;
    const float* Hb = Hg + (size_t)b * 5 * 512;

    for (int p = wave; p < 10; p += 4) {
        int n = p >> 1, ty = p & 1;
        const float* hv = Hb + n * 512;
        const float* av = ty ? adst : asrc;
        float s = 0.f;
#pragma unroll
        for (int j = 0; j < 8; ++j) s += hv[lane + 64 * j] * av[lane + 64 * j];
        for (int off = 32; off > 0; off >>= 1) s += __shfl_down(s, off, 64);
        if (lane == 0) { if (ty) sd[n] = s; else ss[n] = s; }
    }
    __syncthreads();

    if (tid < 5) {
        int dn = tid;
        float e[5];
        float mx = -1e30f;
        for (int s = 0; s < 5; ++s) {
            e[s] = lrelu02(ss[s] + sd[dn]);
            mx = fmaxf(mx, e[s]);
        }
        float den = 0.f;
        for (int s = 0; s < 5; ++s) { e[s] = expf(e[s] - mx); den += e[s]; }
        float inv = 1.f / den;
        for (int s = 0; s < 5; ++s) alpha[dn][s] = e[s] * inv;
    }
    __syncthreads();

    for (int d = tid; d < 512; d += 256) {
        float h0 = Hb[0 * 512 + d], h1 = Hb[1 * 512 + d], h2 = Hb[2 * 512 + d];
        float h3 = Hb[3 * 512 + d], h4 = Hb[4 * 512 + d];
        float bd = bias[d];
#pragma unroll
        for (int dn = 0; dn < 5; ++dn) {
            float v = alpha[dn][0] * h0 + alpha[dn][1] * h1 + alpha[dn][2] * h2 +
                      alpha[dn][3] * h3 + alpha[dn][4] * h4 + bd;
            if (RELU) v = fmaxf(v, 0.f);
            out[((size_t)b * 5 + dn) * 512 + d] = v;
        }
    }
}

// ---------------- D2 ---------------------------------------------------------
__global__ __launch_bounds__(64) void final_k(
    const float* __restrict__ hid, const float* __restrict__ w,
    const float* __restrict__ bvec, float* __restrict__ out)
{
    const int b = blockIdx.x;
    const int lane = threadIdx.x;
    const float* h = hid + (size_t)b * 512;
    float a0 = 0.f, a1 = 0.f, a2 = 0.f;
#pragma unroll
    for (int j = 0; j < 8; ++j) {
        int d = lane + 64 * j;
        float x = h[d];
        a0 += x * w[d * 3 + 0];
        a1 += x * w[d * 3 + 1];
        a2 += x * w[d * 3 + 2];
    }
    for (int off = 32; off > 0; off >>= 1) {
        a0 += __shfl_down(a0, off, 64);
        a1 += __shfl_down(a1, off, 64);
        a2 += __shfl_down(a2, off, 64);
    }
    if (lane == 0) {
        out[b * 3 + 0] = a0 + bvec[0];
        out[b * 3 + 1] = a1 + bvec[1];
        out[b * 3 + 2] = a2 + bvec[2];
    }
}

extern "C" void kernel_launch(void* const* d_in, const int* in_sizes, int n_in,
                              void* d_out, int out_size, void* d_ws, size_t ws_size,
                              hipStream_t stream) {
    const float* text   = (const float*)d_in[0];
    const float* image  = (const float*)d_in[1];
    const float* imgtxt = (const float*)d_in[2];
    const float* face   = (const float*)d_in[3];
    const float* word   = (const float*)d_in[4];
    const float* obj    = (const float*)d_in[5];
    const float* ow_W    = (const float*)d_in[6];
    const float* ow_asrc = (const float*)d_in[7];
    const float* ow_adst = (const float*)d_in[8];
    const float* ow_b    = (const float*)d_in[9];
    const float* g1_W    = (const float*)d_in[10];
    const float* g1_asrc = (const float*)d_in[11];
    const float* g1_adst = (const float*)d_in[12];
    const float* g1_b    = (const float*)d_in[13];
    const float* g2_W    = (const float*)d_in[14];
    const float* g2_asrc = (const float*)d_in[15];
    const float* g2_adst = (const float*)d_in[16];
    const float* g2_b    = (const float*)d_in[17];
    const float* m1_W    = (const float*)d_in[18];
    const float* m1_b    = (const float*)d_in[19];
    const float* m2_W    = (const float*)d_in[20];
    const float* m2_b    = (const float*)d_in[21];

    float* ws = (float*)d_ws;
    float* H    = ws;                    // 14,680,064 f32
    float* hout = H + 14680064;          //  7,340,032 f32
    float* algn = hout + 7340032;        //    262,144 f32
    unsigned short* owWt = (unsigned short*)(algn + 262144);
    unsigned short* g1Wt = owWt + 524288;    // 1024*512
    unsigned short* g2Wt = g1Wt + 278528;    // 512*544
    unsigned short* m1Wt = g2Wt + 262144;    // 512*512 ; m1Wt: 512*2560
    // alias region over H (H dead after A2/A3):
    float* x5    = H;                    // 2560*544 = 1,392,640
    float* hg    = x5 + 1392640;         // 1,310,720
    float* h1    = hg + 1310720;         // 1,310,720
    float* fused = h1 + 1310720;         // 1,310,720
    float* hid   = fused + 1310720;      //   262,144

    // Weight transpose+convert (independent of data pipeline)
    wt_conv<<<dim3(16, 32), 256, 0, stream>>>(ow_W, 512, 1024, 512, owWt);
    wt_conv<<<dim3(17, 16), 256, 0, stream>>>(g1_W, 513, 512, 544, g1Wt);
    wt_conv<<<dim3(16, 16), 256, 0, stream>>>(g2_W, 512, 512, 512, g2Wt);
    wt_conv<<<dim3(80, 16), 256, 0, stream>>>(m1_W, 2560, 512, 2560, m1Wt);

    // A1
    gemm_bf16<128, 128, 0, 1><<<dim3(1024 / 128, 14336 / 128), 256, 0, stream>>>(
        nullptr, 0, owWt, 512, H, 1024, 14336, 1024, 512, nullptr, word, obj);
    // A2
    ow_gat<<<B_SAMP, 256, 0, stream>>>(H, ow_asrc, ow_adst, ow_b, hout);
    // A3
    attn_align<<<B_SAMP, 256, 0, stream>>>(hout, algn);
    // B
    build_x5<<<(B_SAMP * 5) / 4, 256, 0, stream>>>(text, image, imgtxt, face, algn, x5);
    // C1
    gemm_bf16<128, 128, 0, 0><<<dim3(512 / 128, 2560 / 128), 256, 0, stream>>>(
        x5, 544, g1Wt, 544, hg, 512, 2560, 512, 544, nullptr, nullptr, nullptr);
    // C2
    g5_gat<1><<<B_SAMP, 256, 0, stream>>>(hg, g1_asrc, g1_adst, g1_b, h1);
    // C3
    gemm_bf16<128, 128, 0, 0><<<dim3(512 / 128, 2560 / 128), 256, 0, stream>>>(
        h1, 512, g2Wt, 512, hg, 512, 2560, 512, 512, nullptr, nullptr, nullptr);
    // C4
    g5_gat<0><<<B_SAMP, 256, 0, stream>>>(hg, g2_asrc, g2_adst, g2_b, fused);
    // D1 (64x64 tile -> 64 blocks)
    gemm_bf16<64, 64, 1, 0><<<dim3(512 / 64, 512 / 64), 256, 0, stream>>>(
        fused, 2560, m1Wt, 2560, hid, 512, 512, 512, 2560, m1_b, nullptr, nullptr);
    // D2
    final_k<<<B_SAMP, 64, 0, stream>>>(hid, m2_W, m2_b, (float*)d_out);
}

// Round 4
// 161.272 us; speedup vs baseline: 5.0398x; 1.5514x over previous
//
#include <hip/hip_runtime.h>
#include <hip/hip_bf16.h>
#include <math.h>

// ---------------------------------------------------------------------------
// SentiGAT — round 3: round-2 structure with the D1 lda bug fixed (512->2560).
//  V : v[t] = W_h @ a (4 matvecs)                       (ow_vvec)
//  P : per-sample scores+alpha+aggregate -> zcat bf16   (ow_pre)
//  A1: hout = zcat @ [0.5W0;0.5W1] + ow_b  (14336x512x1024 MFMA)
//  A3: attn softmax + aligned                           (attn_align)
//  B : ind_norm -> x5b bf16 (B*5,544)
//  C1/C3: MFMA GEMMs (bf16 A), C2/C4: 5-node GAT (bf16 out)
//  D1: split-K x4 MFMA + reduce,  D2: final projection
// ---------------------------------------------------------------------------

#define B_SAMP 512

typedef short short8 __attribute__((ext_vector_type(8)));
typedef float floatx4 __attribute__((ext_vector_type(4)));

__device__ __forceinline__ float lrelu02(float x) { return x > 0.f ? x : 0.2f * x; }

__device__ __forceinline__ unsigned short cvt_bf16(float f) {
    union { float f; unsigned int u; } v; v.f = f;
    unsigned int u = v.u;
    return (unsigned short)((u + 0x7FFFu + ((u >> 16) & 1u)) >> 16);  // RNE
}

// ---------------- weight transpose+convert: fp32 [K][ldw] -> bf16 [N][Kpad] -
__global__ __launch_bounds__(256) void wt_conv(
    const float* __restrict__ W, int ldw, int K, int Kpad, int koff, float scale,
    unsigned short* __restrict__ Wt)
{
    __shared__ float T[32][33];
    const int tid = threadIdx.x;
    const int k0 = blockIdx.x * 32;
    const int n0 = blockIdx.y * 32;
    {
        int kr = tid >> 3, nc = (tid & 7) * 4;
        float4 v = make_float4(0.f, 0.f, 0.f, 0.f);
        if (k0 + kr < K) v = *(const float4*)(W + (size_t)(k0 + kr) * ldw + n0 + nc);
        T[nc + 0][kr] = v.x * scale; T[nc + 1][kr] = v.y * scale;
        T[nc + 2][kr] = v.z * scale; T[nc + 3][kr] = v.w * scale;
    }
    __syncthreads();
    {
        int nr = tid >> 3, kc = (tid & 7) * 4;
        ushort4 w;
        w.x = cvt_bf16(T[nr][kc + 0]);
        w.y = cvt_bf16(T[nr][kc + 1]);
        w.z = cvt_bf16(T[nr][kc + 2]);
        w.w = cvt_bf16(T[nr][kc + 3]);
        *(ushort4*)(Wt + (size_t)(n0 + nr) * Kpad + koff + k0 + kc) = w;
    }
}

// ---------------- V: v[t*512+k] = sum_d W[k][ (t&1)*512 + d ] * a[t][d] -----
__global__ __launch_bounds__(256) void ow_vvec(
    const float* __restrict__ W,      // [512][1024]
    const float* __restrict__ asrc,   // [2][512]
    const float* __restrict__ adst,   // [2][512]
    float* __restrict__ vg)           // [4*512]
{
    const int lane = threadIdx.x & 63;
    const int gw = blockIdx.x * 4 + (threadIdx.x >> 6);
    for (int idx = gw; idx < 2048; idx += 512) {
        int t = idx >> 9, k = idx & 511;
        const float* a = (t < 2) ? (asrc + t * 512) : (adst + (t - 2) * 512);
        const float* wr = W + (size_t)k * 1024 + (t & 1) * 512;
        float s = 0.f;
#pragma unroll
        for (int j = 0; j < 8; ++j) s += wr[lane + 64 * j] * a[lane + 64 * j];
        for (int off = 32; off > 0; off >>= 1) s += __shfl_down(s, off, 64);
        if (lane == 0) vg[idx] = s;
    }
}

// ---------------- P: per-sample scores + alpha + input-space aggregate ------
__global__ __launch_bounds__(256) void ow_pre(
    const float* __restrict__ wf, const float* __restrict__ of,
    const float* __restrict__ vg,
    unsigned short* __restrict__ zcat)   // [B*28][1024] bf16
{
    const int b = blockIdx.x;
    __shared__ float Xs[28][512];
    __shared__ float ss[28][2], sd[28][2];
    __shared__ float alpha[16][2][13];

    const int tid = threadIdx.x;
    const int lane = tid & 63;
    const int wid = tid >> 6;

    for (int idx = tid; idx < 28 * 128; idx += 256) {
        int n = idx >> 7, c = (idx & 127) * 4;
        const float* src = (n < 12) ? (wf + ((size_t)b * 12 + n) * 512)
                                    : (of + ((size_t)b * 16 + (n - 12)) * 512);
        *(float4*)&Xs[n][c] = *(const float4*)(src + c);
    }
    __syncthreads();

    for (int p = wid; p < 112; p += 4) {
        int n = p >> 2, t = p & 3;
        const float* vv = vg + t * 512;
        float s = 0.f;
#pragma unroll
        for (int j = 0; j < 8; ++j) s += Xs[n][lane + 64 * j] * vv[lane + 64 * j];
        for (int off = 32; off > 0; off >>= 1) s += __shfl_down(s, off, 64);
        if (lane == 0) { if (t < 2) ss[n][t] = s; else sd[n][t - 2] = s; }
    }
    __syncthreads();

    if (tid < 32) {
        int w = tid >> 1, h = tid & 1;
        float sdv = sd[12 + w][h];
        float e[13];
        float mx = -1e30f;
        for (int j = 0; j < 12; ++j) {
            e[j] = lrelu02(ss[j][h] + sdv);
            mx = fmaxf(mx, e[j]);
        }
        e[12] = lrelu02(ss[12 + w][h] + sdv);
        mx = fmaxf(mx, e[12]);
        float den = 0.f;
        for (int j = 0; j < 13; ++j) { e[j] = expf(e[j] - mx); den += e[j]; }
        float inv = 1.f / den;
        for (int j = 0; j < 13; ++j) alpha[w][h][j] = e[j] * inv;
    }
    __syncthreads();

    unsigned short* zb = zcat + (size_t)b * 28 * 1024;
    // self-only rows (nodes 0..11): z = [x | x]
    for (int idx = tid; idx < 12 * 1024; idx += 256) {
        int n = idx >> 10, d = idx & 511;
        zb[idx] = cvt_bf16(Xs[n][d]);
    }
    // aggregating rows (nodes 12..27): z[w,h,d] = a_self*x_self + sum_j a_j x_j
    for (int c = tid; c < 1024; c += 256) {
        int h = c >> 9, d = c & 511;
        float xr[12];
#pragma unroll
        for (int j = 0; j < 12; ++j) xr[j] = Xs[j][d];
#pragma unroll 4
        for (int w = 0; w < 16; ++w) {
            float a = alpha[w][h][12] * Xs[12 + w][d];
#pragma unroll
            for (int j = 0; j < 12; ++j) a += alpha[w][h][j] * xr[j];
            zb[(size_t)(12 + w) * 1024 + c] = cvt_bf16(a);
        }
    }
}

// ---------------- bf16 MFMA GEMM: C = A @ Bt^T (+bias)(+relu), split-K ------
template <int BM, int BN, int RELU, int SPLITK>
__global__ __launch_bounds__(256) void gemm_bb(
    const unsigned short* __restrict__ A, int lda,
    const unsigned short* __restrict__ Bt, int ldbt,
    float* __restrict__ C, int ldc,
    int M, int N, int K,
    const float* __restrict__ bias)
{
    constexpr int WM = BM / 2, WN = BN / 2;
    constexpr int MF = WM / 16, NF = WN / 16;

    __shared__ unsigned short As[BM][40];
    __shared__ unsigned short Bs[BN][40];

    const int tid = threadIdx.x;
    const int n0 = blockIdx.x * BN;
    const int m0 = blockIdx.y * BM;
    const int lane = tid & 63;
    const int wid = tid >> 6;
    const int wm = (wid & 1) * WM;
    const int wn = (wid >> 1) * WN;
    const int fr = lane & 15;
    const int kq = (lane >> 4) * 8;

    floatx4 acc[MF][NF];
#pragma unroll
    for (int i = 0; i < MF; ++i)
#pragma unroll
        for (int j = 0; j < NF; ++j) acc[i][j] = (floatx4){0.f, 0.f, 0.f, 0.f};

    const int kchunk = K / SPLITK;
    const int kbeg = (SPLITK > 1) ? blockIdx.z * kchunk : 0;
    const int kend = kbeg + kchunk;
    if (SPLITK > 1) C += (size_t)blockIdx.z * M * ldc;

    for (int k0 = kbeg; k0 < kend; k0 += 32) {
#pragma unroll
        for (int c = tid; c < BM * 4; c += 256) {
            int r = c >> 2, col = (c & 3) * 8;
            *(short8*)&As[r][col] = *(const short8*)(A + (size_t)(m0 + r) * lda + k0 + col);
        }
#pragma unroll
        for (int c = tid; c < BN * 4; c += 256) {
            int r = c >> 2, col = (c & 3) * 8;
            *(short8*)&Bs[r][col] = *(const short8*)(Bt + (size_t)(n0 + r) * ldbt + k0 + col);
        }
        __syncthreads();

        short8 af[MF], bf[NF];
#pragma unroll
        for (int i = 0; i < MF; ++i)
            af[i] = *(const short8*)&As[wm + i * 16 + fr][kq];
#pragma unroll
        for (int j = 0; j < NF; ++j)
            bf[j] = *(const short8*)&Bs[wn + j * 16 + fr][kq];
#pragma unroll
        for (int i = 0; i < MF; ++i)
#pragma unroll
            for (int j = 0; j < NF; ++j)
                acc[i][j] = __builtin_amdgcn_mfma_f32_16x16x32_bf16(
                    af[i], bf[j], acc[i][j], 0, 0, 0);
        __syncthreads();
    }

    const int fq = lane >> 4;
#pragma unroll
    for (int i = 0; i < MF; ++i) {
#pragma unroll
        for (int j = 0; j < NF; ++j) {
#pragma unroll
            for (int q = 0; q < 4; ++q) {
                int row = m0 + wm + i * 16 + fq * 4 + q;
                int col = n0 + wn + j * 16 + fr;
                float v = acc[i][j][q];
                if (SPLITK == 1 && bias) v += bias[col];
                if (RELU) v = fmaxf(v, 0.f);
                C[(size_t)row * ldc + col] = v;
            }
        }
    }
}

// ---------------- A3: 12x16 attention + aligned -----------------------------
__global__ __launch_bounds__(256) void attn_align(
    const float* __restrict__ hout, float* __restrict__ aligned)
{
    const int b = blockIdx.x;
    __shared__ float uo[12][520];
    __shared__ float uw[16][520];
    __shared__ float S[12][16];
    __shared__ float w16[16];

    const int tid = threadIdx.x;
    const float* hb = hout + (size_t)b * 28 * 512;

    for (int idx = tid; idx < 28 * 128; idx += 256) {
        int n = idx >> 7, c = (idx & 127) * 4;
        float* row = (n < 12) ? &uo[n][0] : &uw[n - 12][0];
        *(float4*)&row[c] = *(const float4*)(hb + (size_t)n * 512 + c);
    }
    __syncthreads();

    if (tid < 192) {
        int i = tid >> 4, j = tid & 15;
        float s = 0.f;
        for (int d = 0; d < 128; ++d) {
            float4 a = *(const float4*)&uo[i][d * 4];
            float4 c = *(const float4*)&uw[j][d * 4];
            s += a.x * c.x + a.y * c.y + a.z * c.z + a.w * c.w;
        }
        S[i][j] = s;
    }
    __syncthreads();

    if (tid < 12) {
        float mx = -1e30f;
        for (int j = 0; j < 16; ++j) mx = fmaxf(mx, S[tid][j]);
        float den = 0.f;
        for (int j = 0; j < 16; ++j) { float p = expf(S[tid][j] - mx); S[tid][j] = p; den += p; }
        float inv = 1.f / den;
        for (int j = 0; j < 16; ++j) S[tid][j] *= inv;
    }
    __syncthreads();

    if (tid < 16) {
        float s = 0.f;
        for (int i = 0; i < 12; ++i) s += S[i][tid];
        w16[tid] = s * (1.f / 12.f);
    }
    __syncthreads();

    for (int d = tid; d < 512; d += 256) {
        float s = 0.f;
#pragma unroll
        for (int j = 0; j < 16; ++j) s += w16[j] * uw[j][d];
        aligned[(size_t)b * 512 + d] = s;
    }
}

// ---------------- B: ind_norm -> x5b bf16 (B*5, 544) ------------------------
__global__ __launch_bounds__(256) void build_x5(
    const float* __restrict__ t, const float* __restrict__ im,
    const float* __restrict__ it, const float* __restrict__ fa,
    const float* __restrict__ al, unsigned short* __restrict__ x5)
{
    int gw = (int)((blockIdx.x * 256 + threadIdx.x) >> 6);
    int lane = threadIdx.x & 63;
    if (gw >= B_SAMP * 5) return;
    int b = gw / 5, f = gw - b * 5;
    const float* src = (f == 0) ? t : (f == 1) ? im : (f == 2) ? it : (f == 3) ? fa : al;
    src += (size_t)b * 512;

    float vals[8];
    float sum = 0.f, sq = 0.f;
#pragma unroll
    for (int j = 0; j < 8; ++j) {
        float v = src[lane + 64 * j];
        vals[j] = v;
        sum += v;
        sq += v * v;
    }
#pragma unroll
    for (int off = 32; off > 0; off >>= 1) {
        sum += __shfl_xor(sum, off, 64);
        sq  += __shfl_xor(sq,  off, 64);
    }
    float v = (sum != 0.f) ? 1.f : 0.f;
    float nrm = fmaxf(sqrtf(sq + v * v), 1e-12f);
    float inv = 1.f / nrm;
    unsigned short* dst = x5 + (size_t)gw * 544;
#pragma unroll
    for (int j = 0; j < 8; ++j) dst[lane + 64 * j] = cvt_bf16(vals[j] * inv);
    if (lane == 0) dst[512] = cvt_bf16(v * inv);
    else if (lane < 32) dst[512 + lane] = 0;
}

// ---------------- C2/C4: 5-node complete-graph GAT --------------------------
template <int RELU, int OBF16>
__global__ __launch_bounds__(256) void g5_gat(
    const float* __restrict__ Hg,
    const float* __restrict__ asrc, const float* __restrict__ adst,
    const float* __restrict__ bias, void* __restrict__ outp)
{
    const int b = blockIdx.x;
    __shared__ float ss[5], sd[5];
    __shared__ float alpha[5][5];

    const int tid = threadIdx.x;
    const int lane = tid & 63;
    const int wave = tid >> 6;
    const float* Hb = Hg + (size_t)b * 5 * 512;

    for (int p = wave; p < 10; p += 4) {
        int n = p >> 1, ty = p & 1;
        const float* hv = Hb + n * 512;
        const float* av = ty ? adst : asrc;
        float s = 0.f;
#pragma unroll
        for (int j = 0; j < 8; ++j) s += hv[lane + 64 * j] * av[lane + 64 * j];
        for (int off = 32; off > 0; off >>= 1) s += __shfl_down(s, off, 64);
        if (lane == 0) { if (ty) sd[n] = s; else ss[n] = s; }
    }
    __syncthreads();

    if (tid < 5) {
        int dn = tid;
        float e[5];
        float mx = -1e30f;
        for (int s = 0; s < 5; ++s) {
            e[s] = lrelu02(ss[s] + sd[dn]);
            mx = fmaxf(mx, e[s]);
        }
        float den = 0.f;
        for (int s = 0; s < 5; ++s) { e[s] = expf(e[s] - mx); den += e[s]; }
        float inv = 1.f / den;
        for (int s = 0; s < 5; ++s) alpha[dn][s] = e[s] * inv;
    }
    __syncthreads();

    for (int d = tid; d < 512; d += 256) {
        float h0 = Hb[0 * 512 + d], h1 = Hb[1 * 512 + d], h2 = Hb[2 * 512 + d];
        float h3 = Hb[3 * 512 + d], h4 = Hb[4 * 512 + d];
        float bd = bias[d];
#pragma unroll
        for (int dn = 0; dn < 5; ++dn) {
            float v = alpha[dn][0] * h0 + alpha[dn][1] * h1 + alpha[dn][2] * h2 +
                      alpha[dn][3] * h3 + alpha[dn][4] * h4 + bd;
            if (RELU) v = fmaxf(v, 0.f);
            size_t oi = ((size_t)b * 5 + dn) * 512 + d;
            if (OBF16) ((unsigned short*)outp)[oi] = cvt_bf16(v);
            else ((float*)outp)[oi] = v;
        }
    }
}

// ---------------- D1 reduce: hid = relu(sum parts + bias) -------------------
__global__ __launch_bounds__(256) void d1_reduce(
    const float* __restrict__ parts, const float* __restrict__ bias,
    float* __restrict__ hid)
{
    int idx = blockIdx.x * 256 + threadIdx.x;   // over 65536 float4
    int e0 = idx * 4;
    float4 a = *(const float4*)(parts + e0);
    float4 b = *(const float4*)(parts + 262144 + e0);
    float4 c = *(const float4*)(parts + 524288 + e0);
    float4 d = *(const float4*)(parts + 786432 + e0);
    float4 bv = *(const float4*)(bias + (e0 & 511));
    float4 o;
    o.x = fmaxf(a.x + b.x + c.x + d.x + bv.x, 0.f);
    o.y = fmaxf(a.y + b.y + c.y + d.y + bv.y, 0.f);
    o.z = fmaxf(a.z + b.z + c.z + d.z + bv.z, 0.f);
    o.w = fmaxf(a.w + b.w + c.w + d.w + bv.w, 0.f);
    *(float4*)(hid + e0) = o;
}

// ---------------- D2 ---------------------------------------------------------
__global__ __launch_bounds__(64) void final_k(
    const float* __restrict__ hid, const float* __restrict__ w,
    const float* __restrict__ bvec, float* __restrict__ out)
{
    const int b = blockIdx.x;
    const int lane = threadIdx.x;
    const float* h = hid + (size_t)b * 512;
    float a0 = 0.f, a1 = 0.f, a2 = 0.f;
#pragma unroll
    for (int j = 0; j < 8; ++j) {
        int d = lane + 64 * j;
        float x = h[d];
        a0 += x * w[d * 3 + 0];
        a1 += x * w[d * 3 + 1];
        a2 += x * w[d * 3 + 2];
    }
    for (int off = 32; off > 0; off >>= 1) {
        a0 += __shfl_down(a0, off, 64);
        a1 += __shfl_down(a1, off, 64);
        a2 += __shfl_down(a2, off, 64);
    }
    if (lane == 0) {
        out[b * 3 + 0] = a0 + bvec[0];
        out[b * 3 + 1] = a1 + bvec[1];
        out[b * 3 + 2] = a2 + bvec[2];
    }
}

extern "C" void kernel_launch(void* const* d_in, const int* in_sizes, int n_in,
                              void* d_out, int out_size, void* d_ws, size_t ws_size,
                              hipStream_t stream) {
    const float* text   = (const float*)d_in[0];
    const float* image  = (const float*)d_in[1];
    const float* imgtxt = (const float*)d_in[2];
    const float* face   = (const float*)d_in[3];
    const float* word   = (const float*)d_in[4];
    const float* obj    = (const float*)d_in[5];
    const float* ow_W    = (const float*)d_in[6];
    const float* ow_asrc = (const float*)d_in[7];
    const float* ow_adst = (const float*)d_in[8];
    const float* ow_b    = (const float*)d_in[9];
    const float* g1_W    = (const float*)d_in[10];
    const float* g1_asrc = (const float*)d_in[11];
    const float* g1_adst = (const float*)d_in[12];
    const float* g1_b    = (const float*)d_in[13];
    const float* g2_W    = (const float*)d_in[14];
    const float* g2_asrc = (const float*)d_in[15];
    const float* g2_adst = (const float*)d_in[16];
    const float* g2_b    = (const float*)d_in[17];
    const float* m1_W    = (const float*)d_in[18];
    const float* m1_b    = (const float*)d_in[19];
    const float* m2_W    = (const float*)d_in[20];
    const float* m2_b    = (const float*)d_in[21];

    float* ws = (float*)d_ws;
    float* vg = ws;                                         // 2048 f
    unsigned short* owWt = (unsigned short*)(ws + 2048);    // 512x1024
    unsigned short* g1Wt = owWt + 524288;                   // 512x544
    unsigned short* g2Wt = g1Wt + 278528;                   // 512x512
    unsigned short* m1Wt = g2Wt + 262144;                   // 512x2560
    unsigned short* zcat = m1Wt + 1310720;                  // 14336x1024
    unsigned short* x5b  = zcat + 14680064;                 // 2560x544
    unsigned short* h1b  = x5b + 1392640;                   // 2560x512
    unsigned short* fsb  = h1b + 1310720;                   // 2560x512
    float* hout = (float*)(fsb + 1310720);                  // 14336x512 f
    float* algn = hout + 7340032;                           // 512x512 f
    float* hg   = algn + 262144;                            // 2560x512 f
    float* hidp = hg + 1310720;                             // 4x512x512 f
    float* hid  = hidp + 1048576;                           // 512x512 f

    // weight prep (independent)
    ow_vvec<<<128, 256, 0, stream>>>(ow_W, ow_asrc, ow_adst, vg);
    wt_conv<<<dim3(16, 16), 256, 0, stream>>>(ow_W,       1024, 512, 1024,   0, 0.5f, owWt);
    wt_conv<<<dim3(16, 16), 256, 0, stream>>>(ow_W + 512, 1024, 512, 1024, 512, 0.5f, owWt);
    wt_conv<<<dim3(17, 16), 256, 0, stream>>>(g1_W, 512, 513,  544, 0, 1.0f, g1Wt);
    wt_conv<<<dim3(16, 16), 256, 0, stream>>>(g2_W, 512, 512,  512, 0, 1.0f, g2Wt);
    wt_conv<<<dim3(80, 16), 256, 0, stream>>>(m1_W, 512, 2560, 2560, 0, 1.0f, m1Wt);

    // stage A
    ow_pre<<<B_SAMP, 256, 0, stream>>>(word, obj, vg, zcat);
    gemm_bb<128, 128, 0, 1><<<dim3(4, 112), 256, 0, stream>>>(
        zcat, 1024, owWt, 1024, hout, 512, 14336, 512, 1024, ow_b);
    attn_align<<<B_SAMP, 256, 0, stream>>>(hout, algn);

    // stage B
    build_x5<<<(B_SAMP * 5) / 4, 256, 0, stream>>>(text, image, imgtxt, face, algn, x5b);

    // stage C
    gemm_bb<64, 64, 0, 1><<<dim3(8, 40), 256, 0, stream>>>(
        x5b, 544, g1Wt, 544, hg, 512, 2560, 512, 544, nullptr);
    g5_gat<1, 1><<<B_SAMP, 256, 0, stream>>>(hg, g1_asrc, g1_adst, g1_b, h1b);
    gemm_bb<64, 64, 0, 1><<<dim3(8, 40), 256, 0, stream>>>(
        h1b, 512, g2Wt, 512, hg, 512, 2560, 512, 512, nullptr);
    g5_gat<0, 1><<<B_SAMP, 256, 0, stream>>>(hg, g2_asrc, g2_adst, g2_b, fsb);

    // stage D  (fsb viewed as [512][2560] -> lda = 2560)
    gemm_bb<64, 64, 0, 4><<<dim3(8, 8, 4), 256, 0, stream>>>(
        fsb, 2560, m1Wt, 2560, hidp, 512, 512, 512, 2560, nullptr);
    d1_reduce<<<256, 256, 0, stream>>>(hidp, m1_b, hid);
    final_k<<<B_SAMP, 64, 0, stream>>>(hid, m2_W, m2_b, (float*)d_out);
}

// Round 5
// 126.855 us; speedup vs baseline: 6.4071x; 1.2713x over previous
//
#include <hip/hip_runtime.h>
#include <hip/hip_bf16.h>
#include <math.h>

// ---------------------------------------------------------------------------
// SentiGAT — round 4: pipelined GEMM (1-barrier double-buffer, reg prefetch),
// M-major grid for XCD-L2 A reuse, merged prep / attn+x5 / reduce+final.
// ---------------------------------------------------------------------------

#define B_SAMP 512

typedef short short8 __attribute__((ext_vector_type(8)));
typedef float floatx4 __attribute__((ext_vector_type(4)));

__device__ __forceinline__ float lrelu02(float x) { return x > 0.f ? x : 0.2f * x; }

__device__ __forceinline__ unsigned short cvt_bf16(float f) {
    union { float f; unsigned int u; } v; v.f = f;
    unsigned int u = v.u;
    return (unsigned short)((u + 0x7FFFu + ((u >> 16) & 1u)) >> 16);  // RNE
}

// ---------------- merged prep: ow_vvec + all weight transposes --------------
// blocks [0,128): vvec; [128,2448): wt tiles.
__global__ __launch_bounds__(256) void prep(
    const float* __restrict__ ow_W, const float* __restrict__ ow_asrc,
    const float* __restrict__ ow_adst,
    const float* __restrict__ g1_W, const float* __restrict__ g2_W,
    const float* __restrict__ m1_W,
    float* __restrict__ vg, unsigned short* __restrict__ owWt,
    unsigned short* __restrict__ g1Wt, unsigned short* __restrict__ g2Wt,
    unsigned short* __restrict__ m1Wt)
{
    __shared__ float T[32][33];
    const int tid = threadIdx.x;
    int bid = blockIdx.x;

    if (bid < 128) {
        // v[t*512+k] = sum_d W[k][(t&1)*512+d] * a[t][d]
        const int lane = tid & 63;
        const int gw = bid * 4 + (tid >> 6);
        for (int idx = gw; idx < 2048; idx += 512) {
            int t = idx >> 9, k = idx & 511;
            const float* a = (t < 2) ? (ow_asrc + t * 512) : (ow_adst + (t - 2) * 512);
            const float* wr = ow_W + (size_t)k * 1024 + (t & 1) * 512;
            float s = 0.f;
#pragma unroll
            for (int j = 0; j < 8; ++j) s += wr[lane + 64 * j] * a[lane + 64 * j];
            for (int off = 32; off > 0; off >>= 1) s += __shfl_down(s, off, 64);
            if (lane == 0) vg[idx] = s;
        }
        return;
    }
    bid -= 128;
    const float* W; int ldw, K, Kpad, koff, ktiles; float scale; unsigned short* Wt;
    if (bid < 256)        { W = ow_W;       ldw = 1024; K = 512;  Kpad = 1024; koff = 0;   scale = 0.5f; Wt = owWt; ktiles = 16; }
    else if (bid < 512)   { bid -= 256;  W = ow_W + 512; ldw = 1024; K = 512;  Kpad = 1024; koff = 512; scale = 0.5f; Wt = owWt; ktiles = 16; }
    else if (bid < 784)   { bid -= 512;  W = g1_W; ldw = 512; K = 513;  Kpad = 544;  koff = 0; scale = 1.f; Wt = g1Wt; ktiles = 17; }
    else if (bid < 1040)  { bid -= 784;  W = g2_W; ldw = 512; K = 512;  Kpad = 512;  koff = 0; scale = 1.f; Wt = g2Wt; ktiles = 16; }
    else                  { bid -= 1040; W = m1_W; ldw = 512; K = 2560; Kpad = 2560; koff = 0; scale = 1.f; Wt = m1Wt; ktiles = 80; }
    const int k0 = (bid % ktiles) * 32;
    const int n0 = (bid / ktiles) * 32;
    {
        int kr = tid >> 3, nc = (tid & 7) * 4;
        float4 v = make_float4(0.f, 0.f, 0.f, 0.f);
        if (k0 + kr < K) v = *(const float4*)(W + (size_t)(k0 + kr) * ldw + n0 + nc);
        T[nc + 0][kr] = v.x * scale; T[nc + 1][kr] = v.y * scale;
        T[nc + 2][kr] = v.z * scale; T[nc + 3][kr] = v.w * scale;
    }
    __syncthreads();
    {
        int nr = tid >> 3, kc = (tid & 7) * 4;
        ushort4 w;
        w.x = cvt_bf16(T[nr][kc + 0]);
        w.y = cvt_bf16(T[nr][kc + 1]);
        w.z = cvt_bf16(T[nr][kc + 2]);
        w.w = cvt_bf16(T[nr][kc + 3]);
        *(ushort4*)(Wt + (size_t)(n0 + nr) * Kpad + koff + k0 + kc) = w;
    }
}

// ---------------- ow_pre: scores + alpha + input-space aggregate ------------
__global__ __launch_bounds__(256) void ow_pre(
    const float* __restrict__ wf, const float* __restrict__ of,
    const float* __restrict__ vg,
    unsigned short* __restrict__ zcat)   // [B*28][1024] bf16
{
    const int b = blockIdx.x;
    __shared__ float Xs[28][512];
    __shared__ float ss[28][2], sd[28][2];
    __shared__ float alpha[16][2][13];

    const int tid = threadIdx.x;
    const int lane = tid & 63;
    const int wid = tid >> 6;

    for (int idx = tid; idx < 28 * 128; idx += 256) {
        int n = idx >> 7, c = (idx & 127) * 4;
        const float* src = (n < 12) ? (wf + ((size_t)b * 12 + n) * 512)
                                    : (of + ((size_t)b * 16 + (n - 12)) * 512);
        *(float4*)&Xs[n][c] = *(const float4*)(src + c);
    }
    __syncthreads();

    for (int p = wid; p < 112; p += 4) {
        int n = p >> 2, t = p & 3;
        const float* vv = vg + t * 512;
        float s = 0.f;
#pragma unroll
        for (int j = 0; j < 8; ++j) s += Xs[n][lane + 64 * j] * vv[lane + 64 * j];
        for (int off = 32; off > 0; off >>= 1) s += __shfl_down(s, off, 64);
        if (lane == 0) { if (t < 2) ss[n][t] = s; else sd[n][t - 2] = s; }
    }
    __syncthreads();

    if (tid < 32) {
        int w = tid >> 1, h = tid & 1;
        float sdv = sd[12 + w][h];
        float e[13];
        float mx = -1e30f;
        for (int j = 0; j < 12; ++j) {
            e[j] = lrelu02(ss[j][h] + sdv);
            mx = fmaxf(mx, e[j]);
        }
        e[12] = lrelu02(ss[12 + w][h] + sdv);
        mx = fmaxf(mx, e[12]);
        float den = 0.f;
        for (int j = 0; j < 13; ++j) { e[j] = expf(e[j] - mx); den += e[j]; }
        float inv = 1.f / den;
        for (int j = 0; j < 13; ++j) alpha[w][h][j] = e[j] * inv;
    }
    __syncthreads();

    unsigned short* zb = zcat + (size_t)b * 28 * 1024;
    for (int idx = tid; idx < 12 * 1024; idx += 256) {
        int n = idx >> 10, d = idx & 511;
        zb[idx] = cvt_bf16(Xs[n][d]);
    }
    for (int c = tid; c < 1024; c += 256) {
        int h = c >> 9, d = c & 511;
        float xr[12];
#pragma unroll
        for (int j = 0; j < 12; ++j) xr[j] = Xs[j][d];
#pragma unroll 4
        for (int w = 0; w < 16; ++w) {
            float a = alpha[w][h][12] * Xs[12 + w][d];
#pragma unroll
            for (int j = 0; j < 12; ++j) a += alpha[w][h][j] * xr[j];
            zb[(size_t)(12 + w) * 1024 + c] = cvt_bf16(a);
        }
    }
}

// ---------------- GEMM v2: 1-barrier double-buffered pipeline ---------------
// C[M][ldc] = A[M][lda](bf16) @ Bt[N][ldbt]^T(bf16) (+bias)(+relu), split-K.
// grid: x = M-tiles (fast), y = N-tiles, z = K-split.
template <int BM, int BN, int RELU, int SPLITK>
__global__ __launch_bounds__(256) void gemm_v2(
    const unsigned short* __restrict__ A, int lda,
    const unsigned short* __restrict__ Bt, int ldbt,
    float* __restrict__ C, int ldc,
    int M, int N, int K,
    const float* __restrict__ bias)
{
    constexpr int WM = BM / 2, WN = BN / 2;
    constexpr int MF = WM / 16, NF = WN / 16;
    constexpr int CA = BM / 64, CB = BN / 64;   // 16B chunks per thread

    __shared__ unsigned short As[2][BM][40];
    __shared__ unsigned short Bs[2][BN][40];

    const int tid = threadIdx.x;
    const int m0 = blockIdx.x * BM;
    const int n0 = blockIdx.y * BN;
    const int lane = tid & 63;
    const int wid = tid >> 6;
    const int wm = (wid & 1) * WM;
    const int wn = (wid >> 1) * WN;
    const int fr = lane & 15;
    const int kq = (lane >> 4) * 8;

    const int srow = tid >> 2;        // 0..63
    const int scol = (tid & 3) * 8;   // 0,8,16,24

    const int kchunk = K / SPLITK;
    const int kbeg = (SPLITK > 1) ? blockIdx.z * kchunk : 0;
    const int kend = kbeg + kchunk;
    if (SPLITK > 1) C += (size_t)blockIdx.z * M * ldc;

    short8 ra[CA], rb[CB];
#define LOADAB(K0)                                                                   \
    do {                                                                             \
        _Pragma("unroll")                                                            \
        for (int c = 0; c < CA; ++c)                                                 \
            ra[c] = *(const short8*)(A + (size_t)(m0 + srow + c * 64) * lda + (K0) + scol); \
        _Pragma("unroll")                                                            \
        for (int c = 0; c < CB; ++c)                                                 \
            rb[c] = *(const short8*)(Bt + (size_t)(n0 + srow + c * 64) * ldbt + (K0) + scol); \
    } while (0)

    LOADAB(kbeg);

    floatx4 acc[MF][NF];
#pragma unroll
    for (int i = 0; i < MF; ++i)
#pragma unroll
        for (int j = 0; j < NF; ++j) acc[i][j] = (floatx4){0.f, 0.f, 0.f, 0.f};

    int t = 0;
    for (int k0 = kbeg; k0 < kend; k0 += 32, t ^= 1) {
#pragma unroll
        for (int c = 0; c < CA; ++c) *(short8*)&As[t][srow + c * 64][scol] = ra[c];
#pragma unroll
        for (int c = 0; c < CB; ++c) *(short8*)&Bs[t][srow + c * 64][scol] = rb[c];
        __syncthreads();
        if (k0 + 32 < kend) LOADAB(k0 + 32);   // prefetch flies under ds_read+MFMA

        short8 af[MF], bw[NF];
#pragma unroll
        for (int i = 0; i < MF; ++i)
            af[i] = *(const short8*)&As[t][wm + i * 16 + fr][kq];
#pragma unroll
        for (int j = 0; j < NF; ++j)
            bw[j] = *(const short8*)&Bs[t][wn + j * 16 + fr][kq];
#pragma unroll
        for (int i = 0; i < MF; ++i)
#pragma unroll
            for (int j = 0; j < NF; ++j)
                acc[i][j] = __builtin_amdgcn_mfma_f32_16x16x32_bf16(
                    af[i], bw[j], acc[i][j], 0, 0, 0);
        // no second barrier: buf t is rewritten only after the next sync
    }
#undef LOADAB

    const int fq = lane >> 4;
#pragma unroll
    for (int i = 0; i < MF; ++i) {
#pragma unroll
        for (int j = 0; j < NF; ++j) {
#pragma unroll
            for (int q = 0; q < 4; ++q) {
                int row = m0 + wm + i * 16 + fq * 4 + q;
                int col = n0 + wn + j * 16 + fr;
                float v = acc[i][j][q];
                if (SPLITK == 1 && bias) v += bias[col];
                if (RELU) v = fmaxf(v, 0.f);
                C[(size_t)row * ldc + col] = v;
            }
        }
    }
}

// ---------------- attn + ind_norm fused: hout -> x5b rows -------------------
__global__ __launch_bounds__(256) void attn_x5(
    const float* __restrict__ hout,
    const float* __restrict__ tf, const float* __restrict__ im,
    const float* __restrict__ it, const float* __restrict__ fa,
    unsigned short* __restrict__ x5)
{
    const int b = blockIdx.x;
    __shared__ float uo[12][520];
    __shared__ float uw[16][520];
    __shared__ float S[12][16];
    __shared__ float w16[16];
    __shared__ float al[512];

    const int tid = threadIdx.x;
    const int lane = tid & 63;
    const int wave = tid >> 6;
    const float* hb = hout + (size_t)b * 28 * 512;

    for (int idx = tid; idx < 28 * 128; idx += 256) {
        int n = idx >> 7, c = (idx & 127) * 4;
        float* row = (n < 12) ? &uo[n][0] : &uw[n - 12][0];
        *(float4*)&row[c] = *(const float4*)(hb + (size_t)n * 512 + c);
    }
    __syncthreads();

    if (tid < 192) {
        int i = tid >> 4, j = tid & 15;
        float s = 0.f;
        for (int d = 0; d < 128; ++d) {
            float4 a = *(const float4*)&uo[i][d * 4];
            float4 c = *(const float4*)&uw[j][d * 4];
            s += a.x * c.x + a.y * c.y + a.z * c.z + a.w * c.w;
        }
        S[i][j] = s;
    }
    __syncthreads();

    if (tid < 12) {
        float mx = -1e30f;
        for (int j = 0; j < 16; ++j) mx = fmaxf(mx, S[tid][j]);
        float den = 0.f;
        for (int j = 0; j < 16; ++j) { float p = expf(S[tid][j] - mx); S[tid][j] = p; den += p; }
        float inv = 1.f / den;
        for (int j = 0; j < 16; ++j) S[tid][j] *= inv;
    }
    __syncthreads();

    if (tid < 16) {
        float s = 0.f;
        for (int i = 0; i < 12; ++i) s += S[i][tid];
        w16[tid] = s * (1.f / 12.f);
    }
    __syncthreads();

    for (int d = tid; d < 512; d += 256) {
        float s = 0.f;
#pragma unroll
        for (int j = 0; j < 16; ++j) s += w16[j] * uw[j][d];
        al[d] = s;
    }
    __syncthreads();

    // ind_norm all 5 feats for this sample
    for (int f = wave; f < 5; f += 4) {
        const float* src = (f == 0) ? tf : (f == 1) ? im : (f == 2) ? it : (f == 3) ? fa : nullptr;
        float vals[8];
        float sum = 0.f, sq = 0.f;
#pragma unroll
        for (int j = 0; j < 8; ++j) {
            float v = (f < 4) ? src[(size_t)b * 512 + lane + 64 * j] : al[lane + 64 * j];
            vals[j] = v;
            sum += v;
            sq += v * v;
        }
#pragma unroll
        for (int off = 32; off > 0; off >>= 1) {
            sum += __shfl_xor(sum, off, 64);
            sq  += __shfl_xor(sq,  off, 64);
        }
        float v = (sum != 0.f) ? 1.f : 0.f;
        float nrm = fmaxf(sqrtf(sq + v * v), 1e-12f);
        float inv = 1.f / nrm;
        unsigned short* dst = x5 + ((size_t)b * 5 + f) * 544;
#pragma unroll
        for (int j = 0; j < 8; ++j) dst[lane + 64 * j] = cvt_bf16(vals[j] * inv);
        if (lane == 0) dst[512] = cvt_bf16(v * inv);
        else if (lane < 32) dst[512 + lane] = 0;
    }
}

// ---------------- C2/C4: 5-node complete-graph GAT --------------------------
template <int RELU>
__global__ __launch_bounds__(256) void g5_gat(
    const float* __restrict__ Hg,
    const float* __restrict__ asrc, const float* __restrict__ adst,
    const float* __restrict__ bias, unsigned short* __restrict__ outp)
{
    const int b = blockIdx.x;
    __shared__ float ss[5], sd[5];
    __shared__ float alpha[5][5];

    const int tid = threadIdx.x;
    const int lane = tid & 63;
    const int wave = tid >> 6;
    const float* Hb = Hg + (size_t)b * 5 * 512;

    for (int p = wave; p < 10; p += 4) {
        int n = p >> 1, ty = p & 1;
        const float* hv = Hb + n * 512;
        const float* av = ty ? adst : asrc;
        float s = 0.f;
#pragma unroll
        for (int j = 0; j < 8; ++j) s += hv[lane + 64 * j] * av[lane + 64 * j];
        for (int off = 32; off > 0; off >>= 1) s += __shfl_down(s, off, 64);
        if (lane == 0) { if (ty) sd[n] = s; else ss[n] = s; }
    }
    __syncthreads();

    if (tid < 5) {
        int dn = tid;
        float e[5];
        float mx = -1e30f;
        for (int s = 0; s < 5; ++s) {
            e[s] = lrelu02(ss[s] + sd[dn]);
            mx = fmaxf(mx, e[s]);
        }
        float den = 0.f;
        for (int s = 0; s < 5; ++s) { e[s] = expf(e[s] - mx); den += e[s]; }
        float inv = 1.f / den;
        for (int s = 0; s < 5; ++s) alpha[dn][s] = e[s] * inv;
    }
    __syncthreads();

    for (int d = tid; d < 512; d += 256) {
        float h0 = Hb[0 * 512 + d], h1 = Hb[1 * 512 + d], h2 = Hb[2 * 512 + d];
        float h3 = Hb[3 * 512 + d], h4 = Hb[4 * 512 + d];
        float bd = bias[d];
#pragma unroll
        for (int dn = 0; dn < 5; ++dn) {
            float v = alpha[dn][0] * h0 + alpha[dn][1] * h1 + alpha[dn][2] * h2 +
                      alpha[dn][3] * h3 + alpha[dn][4] * h4 + bd;
            if (RELU) v = fmaxf(v, 0.f);
            outp[((size_t)b * 5 + dn) * 512 + d] = cvt_bf16(v);
        }
    }
}

// ---------------- final: relu(sum split-K parts + b1) @ m2 + b2 -------------
__global__ __launch_bounds__(64) void final2(
    const float* __restrict__ parts, const float* __restrict__ b1,
    const float* __restrict__ w, const float* __restrict__ bvec,
    float* __restrict__ out)
{
    const int b = blockIdx.x;
    const int lane = threadIdx.x;
    float a0 = 0.f, a1 = 0.f, a2 = 0.f;
#pragma unroll
    for (int j = 0; j < 8; ++j) {
        int d = lane + 64 * j;
        size_t o = (size_t)b * 512 + d;
        float x = parts[o] + parts[262144 + o] + parts[524288 + o] + parts[786432 + o] + b1[d];
        x = fmaxf(x, 0.f);
        a0 += x * w[d * 3 + 0];
        a1 += x * w[d * 3 + 1];
        a2 += x * w[d * 3 + 2];
    }
    for (int off = 32; off > 0; off >>= 1) {
        a0 += __shfl_down(a0, off, 64);
        a1 += __shfl_down(a1, off, 64);
        a2 += __shfl_down(a2, off, 64);
    }
    if (lane == 0) {
        out[b * 3 + 0] = a0 + bvec[0];
        out[b * 3 + 1] = a1 + bvec[1];
        out[b * 3 + 2] = a2 + bvec[2];
    }
}

extern "C" void kernel_launch(void* const* d_in, const int* in_sizes, int n_in,
                              void* d_out, int out_size, void* d_ws, size_t ws_size,
                              hipStream_t stream) {
    const float* text   = (const float*)d_in[0];
    const float* image  = (const float*)d_in[1];
    const float* imgtxt = (const float*)d_in[2];
    const float* face   = (const float*)d_in[3];
    const float* word   = (const float*)d_in[4];
    const float* obj    = (const float*)d_in[5];
    const float* ow_W    = (const float*)d_in[6];
    const float* ow_asrc = (const float*)d_in[7];
    const float* ow_adst = (const float*)d_in[8];
    const float* ow_b    = (const float*)d_in[9];
    const float* g1_W    = (const float*)d_in[10];
    const float* g1_asrc = (const float*)d_in[11];
    const float* g1_adst = (const float*)d_in[12];
    const float* g1_b    = (const float*)d_in[13];
    const float* g2_W    = (const float*)d_in[14];
    const float* g2_asrc = (const float*)d_in[15];
    const float* g2_adst = (const float*)d_in[16];
    const float* g2_b    = (const float*)d_in[17];
    const float* m1_W    = (const float*)d_in[18];
    const float* m1_b    = (const float*)d_in[19];
    const float* m2_W    = (const float*)d_in[20];
    const float* m2_b    = (const float*)d_in[21];

    float* ws = (float*)d_ws;
    float* vg = ws;                                         // 2048 f
    unsigned short* owWt = (unsigned short*)(ws + 2048);    // 512x1024
    unsigned short* g1Wt = owWt + 524288;                   // 512x544
    unsigned short* g2Wt = g1Wt + 278528;                   // 512x512
    unsigned short* m1Wt = g2Wt + 262144;                   // 512x2560
    unsigned short* zcat = m1Wt + 1310720;                  // 14336x1024
    unsigned short* x5b  = zcat + 14680064;                 // 2560x544
    unsigned short* h1b  = x5b + 1392640;                   // 2560x512
    unsigned short* fsb  = h1b + 1310720;                   // 2560x512
    float* hout = (float*)(fsb + 1310720);                  // 14336x512 f
    float* hg   = hout + 7340032;                           // 2560x512 f
    float* hidp = hg + 1310720;                             // 4x512x512 f

    // prep: vvec + all weight transposes (one launch)
    prep<<<2448, 256, 0, stream>>>(ow_W, ow_asrc, ow_adst, g1_W, g2_W, m1_W,
                                   vg, owWt, g1Wt, g2Wt, m1Wt);

    // stage A
    ow_pre<<<B_SAMP, 256, 0, stream>>>(word, obj, vg, zcat);
    gemm_v2<128, 128, 0, 1><<<dim3(112, 4), 256, 0, stream>>>(
        zcat, 1024, owWt, 1024, hout, 512, 14336, 512, 1024, ow_b);
    attn_x5<<<B_SAMP, 256, 0, stream>>>(hout, text, image, imgtxt, face, x5b);

    // stage C
    gemm_v2<64, 64, 0, 1><<<dim3(40, 8), 256, 0, stream>>>(
        x5b, 544, g1Wt, 544, hg, 512, 2560, 512, 544, nullptr);
    g5_gat<1><<<B_SAMP, 256, 0, stream>>>(hg, g1_asrc, g1_adst, g1_b, h1b);
    gemm_v2<64, 64, 0, 1><<<dim3(40, 8), 256, 0, stream>>>(
        h1b, 512, g2Wt, 512, hg, 512, 2560, 512, 512, nullptr);
    g5_gat<0><<<B_SAMP, 256, 0, stream>>>(hg, g2_asrc, g2_adst, g2_b, fsb);

    // stage D (fsb viewed as [512][2560])
    gemm_v2<64, 64, 0, 4><<<dim3(8, 8, 4), 256, 0, stream>>>(
        fsb, 2560, m1Wt, 2560, hidp, 512, 512, 512, 2560, nullptr);
    final2<<<B_SAMP, 64, 0, stream>>>(hidp, m1_b, m2_W, m2_b, (float*)d_out);
}